// Round 7
// baseline (434.015 us; speedup 1.0000x reference)
//
#include <hip/hip_runtime.h>

// BConv2d: x (32,32,256,256) f32 NCHW, W (32,32,3,3) binarized to +-1,
// 3x3 'same' conv, out / sqrt(288).
//
// R7: decorrelated deep pipeline. Block = 128px x 16 rows x all 32 co,
// 8 waves = 4 px-segments(32px) x 2 co-halves. 6-slot rolling row window
// (50.7KB -> 3 blocks/CU), TWO rows of loads in flight (reg buffers A/B),
// 1 barrier/iter. write_row's vmcnt drain is for loads issued 2 barriers ago.

typedef __attribute__((ext_vector_type(8))) short short8;
typedef __attribute__((ext_vector_type(4))) float f32x4;

__device__ __forceinline__ short bf16s(float f) {
    unsigned int u = __builtin_bit_cast(unsigned int, f);
    u += 0x7FFFu + ((u >> 16) & 1u);   // RNE
    return (short)(u >> 16);
}

__global__ __launch_bounds__(512, 6)
void bconv2d_kernel(const float* __restrict__ x, const float* __restrict__ wgt,
                    float* __restrict__ out) {
    // unit = slot*528 + pl*4 + (u ^ ((pl>>1)&3)); slot = local_row % 6,
    // local_row = gy - y0 + 1; pl = gx - x0 + 1 (0..129); u = ci/8.
    // Same swizzle family as R4/R6 (bank-clean writes and b128 frag reads).
    __shared__ short8 lds[6 * 528];   // 50688 B

    const int tid = threadIdx.x;
    const int x0  = blockIdx.x * 128;
    const int y0  = blockIdx.y * 16;
    const int n   = blockIdx.z;

    const int l      = tid & 63;
    const int wv     = tid >> 6;
    const int seg    = wv >> 1;        // px segment (32 px)
    const int ch     = wv & 1;         // co half
    const int px0    = seg * 32;       // within-tile px base
    const int lane15 = l & 15;
    const int lhi    = l >> 4;

    // ---- A fragments: sign(W), this wave's co-half, all 9 taps ----
    short8 afrag[3][3];
    {
        const int co  = ch * 16 + lane15;
        const int ci0 = lhi * 8;
        #pragma unroll
        for (int dy = 0; dy < 3; ++dy)
            #pragma unroll
            for (int dx = 0; dx < 3; ++dx) {
                short8 a;
                #pragma unroll
                for (int j = 0; j < 8; ++j) {
                    float wval = wgt[((co * 32 + ci0 + j) * 3 + dy) * 3 + dx];
                    a[j] = (short)((wval > 0.0f) ? 0x3F80 : 0xBF80);
                }
                afrag[dy][dx] = a;
            }
    }

    const float* xn = x + (size_t)n * 32 * 65536;

    // interior ownership: u = tid>>7, gx = x0 + (tid&127)  (256B runs per j)
    // edge ownership (threads 480..487): e=tid-480: side=e&1, u=e>>1
    const int iu  = tid >> 7;
    const int igx = x0 + (tid & 127);
    const bool is_edge = (tid >= 480) && (tid < 488);
    const int  eside   = tid & 1;
    const int  eu      = (tid - 480) >> 1;
    const int  egx     = eside ? x0 + 128 : x0 - 1;

    float rgA[8], rgB[8], reA[8], reB[8];

    auto load_row = [&](int gy, float (&rg)[8], float (&re)[8]) {
        if ((unsigned)gy < 256u) {
            const float* src = xn + ((size_t)(iu * 8) * 256 + gy) * 256 + igx;
            #pragma unroll
            for (int j = 0; j < 8; ++j) rg[j] = src[(size_t)j * 65536];
        } else {
            #pragma unroll
            for (int j = 0; j < 8; ++j) rg[j] = 0.0f;
        }
        if (is_edge) {
            if ((unsigned)gy < 256u && (unsigned)egx < 256u) {
                const float* src = xn + ((size_t)(eu * 8) * 256 + gy) * 256 + egx;
                #pragma unroll
                for (int j = 0; j < 8; ++j) re[j] = src[(size_t)j * 65536];
            } else {
                #pragma unroll
                for (int j = 0; j < 8; ++j) re[j] = 0.0f;
            }
        }
    };

    auto write_row = [&](int slot, float (&rg)[8], float (&re)[8]) {
        const int pl = 1 + (tid & 127);
        short8 v;
        #pragma unroll
        for (int j = 0; j < 8; ++j) v[j] = bf16s(rg[j]);
        lds[slot * 528 + pl * 4 + (iu ^ ((pl >> 1) & 3))] = v;
        if (is_edge) {
            const int ple = eside ? 129 : 0;
            short8 w;
            #pragma unroll
            for (int j = 0; j < 8; ++j) w[j] = bf16s(re[j]);
            lds[slot * 528 + ple * 4 + (eu ^ ((ple >> 1) & 3))] = w;
        }
    };

    const float invdiv = 0.05892556509887896f;   // 1/sqrt(288)

    // compute+store one output row; locals yy..yy+2 -> slots s0,s1,s2
    auto row_cs = [&](int yy, int s0, int s1, int s2) {
        f32x4 acc[2];
        acc[0] = (f32x4)0.0f;
        acc[1] = (f32x4)0.0f;
        const int sb[3] = {s0 * 528, s1 * 528, s2 * 528};
        #pragma unroll
        for (int ss = 0; ss < 3; ++ss)
            #pragma unroll
            for (int dx = 0; dx < 3; ++dx)
                #pragma unroll
                for (int tp = 0; tp < 2; ++tp) {
                    const int pl = px0 + tp * 16 + lane15 + dx;
                    short8 b = lds[sb[ss] + pl * 4 + (lhi ^ ((pl >> 1) & 3))];
                    acc[tp] = __builtin_amdgcn_mfma_f32_16x16x32_bf16(
                        afrag[ss][dx], b, acc[tp], 0, 0, 0);
                }
        const int y = y0 + yy;
        #pragma unroll
        for (int tp = 0; tp < 2; ++tp)
            #pragma unroll
            for (int q = 0; q < 4; ++q) {
                const int co = ch * 16 + lhi * 4 + q;
                out[(((size_t)n * 32 + co) * 256 + y) * 256 + x0 + px0 + tp * 16 + lane15]
                    = acc[tp][q] * invdiv;
            }
    };

    // ---- prologue: locals 0..2 staged; locals 3(A), 4(B) in flight ----
    load_row(y0 - 1, rgA, reA); write_row(0, rgA, reA);
    load_row(y0,     rgA, reA); write_row(1, rgA, reA);
    load_row(y0 + 1, rgA, reA); write_row(2, rgA, reA);
    load_row(y0 + 2, rgA, reA);          // local 3 -> A
    load_row(y0 + 3, rgB, reB);          // local 4 -> B
    __syncthreads();

    // main loop: yy = 0..11 (6 double-iters), loads continue (local yy+5)
    int s = 0;                            // s = yy % 6
    #pragma unroll 1
    for (int it = 0; it < 6; ++it) {
        const int yy = 2 * it;
        const int t0 = s, t1 = (s + 1 < 6) ? s + 1 : s - 5,
                  t2 = (s + 2 < 6) ? s + 2 : s - 4,
                  t3 = (s + 3 < 6) ? s + 3 : s - 3,
                  t4 = (s + 4 < 6) ? s + 4 : s - 2;
        // even row
        write_row(t3, rgA, reA);                   // local yy+3 (row y+2)
        __syncthreads();
        load_row(y0 + yy + 4, rgA, reA);           // local yy+5
        row_cs(yy, t0, t1, t2);
        // odd row
        write_row(t4, rgB, reB);                   // local yy+4
        __syncthreads();
        load_row(y0 + yy + 5, rgB, reB);           // local yy+6
        row_cs(yy + 1, t1, t2, t3);
        s = (s + 2 < 6) ? s + 2 : s - 4;
    }

    // ---- peeled tail: yy = 12..15 (no more loads after local 17) ----
    {
        const int t0 = 0, t1 = 1, t2 = 2, t3 = 3, t4 = 4, t5 = 5;
        // yy=12: write local 15 (slot 3), compute locals 12..14 (0,1,2)
        write_row(t3, rgA, reA);
        __syncthreads();
        load_row(y0 + 16, rgA, reA);               // local 17 (last needed)
        row_cs(12, t0, t1, t2);
        // yy=13: write local 16 (slot 4), compute locals 13..15
        write_row(t4, rgB, reB);
        __syncthreads();
        row_cs(13, t1, t2, t3);
        // yy=14: write local 17 (slot 5), compute locals 14..16
        write_row(t5, rgA, reA);
        __syncthreads();
        row_cs(14, t2, t3, t4);
        // yy=15: compute locals 15..17
        __syncthreads();
        row_cs(15, t3, t4, t5);
    }
}

extern "C" void kernel_launch(void* const* d_in, const int* in_sizes, int n_in,
                              void* d_out, int out_size, void* d_ws, size_t ws_size,
                              hipStream_t stream) {
    const float* x   = (const float*)d_in[0];
    const float* wgt = (const float*)d_in[1];
    float* out = (float*)d_out;
    (void)d_ws; (void)ws_size;
    dim3 grid(2, 16, 32);    // 128px x-strips, 16-row y-strips, images
    dim3 block(512);
    bconv2d_kernel<<<grid, block, 0, stream>>>(x, wgt, out);
}

// Round 8
// 163.195 us; speedup vs baseline: 2.6595x; 2.6595x over previous
//
#include <hip/hip_runtime.h>

// BConv2d: x (32,32,256,256) f32 NCHW, W (32,32,3,3) binarized to +-1,
// 3x3 'same' conv, out / sqrt(288).
//
// R8 = R6 base (full-width rows: per plane-row 1KB contiguous reads, clean
// traffic; 4-slot rolling window; 512 blocks) + two changes:
//  1. raw s_barrier with lgkmcnt(0) ONLY (no vmcnt drain: stores/prefetch
//     loads stay in flight across barriers),
//  2. mfma_f32_32x32x16_bf16: one wave = 32px x all 32co -> halves
//     ds_read_b128 and MFMA count per output row.

typedef __attribute__((ext_vector_type(8))) short short8;
typedef __attribute__((ext_vector_type(16))) float f32x16;

__device__ __forceinline__ short bf16s(float f) {
    unsigned int u = __builtin_bit_cast(unsigned int, f);
    u += 0x7FFFu + ((u >> 16) & 1u);   // RNE
    return (short)(u >> 16);
}

__global__ __launch_bounds__(512, 4)
void bconv2d_kernel(const float* __restrict__ x, const float* __restrict__ wgt,
                    float* __restrict__ out) {
    // unit = slot*1032 + pl*4 + (u ^ ((pl>>1)&3)); slot = gy & 3; pl = gx+1
    // (0..257); u = ci/8 (0..3). Bank-clean for staging writes (R6-verified)
    // and for 32-lane b128 frag reads (every 8 lanes tile all 32 banks).
    __shared__ short8 lds[4 * 1032];   // 66048 B -> 2 blocks/CU

    const int tid = threadIdx.x;
    const int y0  = blockIdx.x * 16;   // 16-row strip
    const int n   = blockIdx.y;        // image

    const int l   = tid & 63;
    const int wv  = tid >> 6;          // 0..7 -> px segment of 32
    const int px0 = wv * 32;
    const int l31 = l & 31;
    const int lh  = l >> 5;            // 0/1

    // ---- A fragments: sign(W), all 9 taps, both ci-halves ----
    // 32x32x16 A layout: lane holds A[row=l&31][k=(l>>5)*8+j]; MFMA kk covers
    // ci = kk*16 .. kk*16+15  =>  ci = kk*16 + lh*8 + j, co = l31.
    short8 afrag[3][3][2];
    {
        #pragma unroll
        for (int dy = 0; dy < 3; ++dy)
            #pragma unroll
            for (int dx = 0; dx < 3; ++dx)
                #pragma unroll
                for (int kk = 0; kk < 2; ++kk) {
                    short8 a;
                    #pragma unroll
                    for (int j = 0; j < 8; ++j) {
                        const int ci = kk * 16 + lh * 8 + j;
                        float wval = wgt[((l31 * 32 + ci) * 3 + dy) * 3 + dx];
                        a[j] = (short)((wval > 0.0f) ? 0x3F80 : 0xBF80);
                    }
                    afrag[dy][dx][kk] = a;
                }
    }

    const float* xn = x + (size_t)n * 32 * 65536;

    // staging ownership: t = tid + k*512 (k=0,1): u = t>>8, gx = t&255.
    // Whole block reads each plane-row as one contiguous 1KB run.
    float rg[2][8];

    auto load_row = [&](int gy) {
        if ((unsigned)gy < 256u) {
            #pragma unroll
            for (int k = 0; k < 2; ++k) {
                const int t  = tid + k * 512;
                const int u  = t >> 8;
                const int gx = t & 255;
                const float* src = xn + ((size_t)(u * 8) * 256 + gy) * 256 + gx;
                #pragma unroll
                for (int j = 0; j < 8; ++j) rg[k][j] = src[(size_t)j * 65536];
            }
        } else {
            #pragma unroll
            for (int k = 0; k < 2; ++k)
                #pragma unroll
                for (int j = 0; j < 8; ++j) rg[k][j] = 0.0f;
        }
    };

    auto write_row = [&](int slot) {
        #pragma unroll
        for (int k = 0; k < 2; ++k) {
            const int t  = tid + k * 512;
            const int u  = t >> 8;
            const int pl = 1 + (t & 255);
            short8 v;
            #pragma unroll
            for (int j = 0; j < 8; ++j) v[j] = bf16s(rg[k][j]);
            lds[slot * 1032 + pl * 4 + (u ^ ((pl >> 1) & 3))] = v;
        }
    };

    // ---- prologue: rows y0-1, y0, y0+1 -> slots 3, 0, 1; zero px edges ----
    load_row(y0 - 1); write_row(3);
    load_row(y0);     write_row(0);
    load_row(y0 + 1); write_row(1);
    if (tid < 32) {   // pl=0 (gx=-1) and pl=257 (gx=256): constant zero
        const int slot = tid & 3;
        const int u    = (tid >> 2) & 3;
        const int pl   = (tid >> 4) ? 257 : 0;
        lds[slot * 1032 + pl * 4 + u] = (short8)0;   // swizzle term 0 here
    }
    asm volatile("s_waitcnt lgkmcnt(0)" ::: "memory");
    __builtin_amdgcn_s_barrier();

    const float invdiv = 0.05892556509887896f;   // 1/sqrt(288)

    #pragma unroll 1
    for (int yy = 0; yy < 16; ++yy) {
        const int y = y0 + yy;

        load_row(y + 2);        // prefetch; consumed by write_row after compute

        f32x16 acc = (f32x16)0.0f;
        #pragma unroll
        for (int ss = 0; ss < 3; ++ss) {              // input row y-1+ss
            const int sbase = ((yy + ss + 3) & 3) * 1032;
            #pragma unroll
            for (int dx = 0; dx < 3; ++dx) {
                const int pl = px0 + l31 + dx;
                #pragma unroll
                for (int kk = 0; kk < 2; ++kk) {
                    const int u = kk * 2 + lh;
                    short8 b = lds[sbase + pl * 4 + (u ^ ((pl >> 1) & 3))];
                    acc = __builtin_amdgcn_mfma_f32_32x32x16_bf16(
                        afrag[ss][dx][kk], b, acc, 0, 0, 0);
                }
            }
        }

        write_row((yy + 2) & 3);   // vmcnt waits land here (after compute)

        // stores: 32x32 C/D layout: col(px)=l&31, row(co)=(q&3)+8*(q>>2)+4*lh.
        // Per q: lanes 0-31 and 32-63 each write one full 128B line.
        #pragma unroll
        for (int q = 0; q < 16; ++q) {
            const int co = (q & 3) + 8 * (q >> 2) + 4 * lh;
            out[(((size_t)n * 32 + co) * 256 + y) * 256 + px0 + l31]
                = acc[q] * invdiv;
        }

        asm volatile("s_waitcnt lgkmcnt(0)" ::: "memory");   // ds ops only
        __builtin_amdgcn_s_barrier();                        // no vmcnt drain
    }
}

extern "C" void kernel_launch(void* const* d_in, const int* in_sizes, int n_in,
                              void* d_out, int out_size, void* d_ws, size_t ws_size,
                              hipStream_t stream) {
    const float* x   = (const float*)d_in[0];
    const float* wgt = (const float*)d_in[1];
    float* out = (float*)d_out;
    (void)d_ws; (void)ws_size;
    dim3 grid(16, 32);     // 16-row strips, images
    dim3 block(512);
    bconv2d_kernel<<<grid, block, 0, stream>>>(x, wgt, out);
}

// Round 9
// 148.776 us; speedup vs baseline: 2.9172x; 1.0969x over previous
//
#include <hip/hip_runtime.h>

// BConv2d: x (32,32,256,256) f32 NCHW, W (32,32,3,3) binarized to +-1,
// 3x3 'same' conv, out / sqrt(288).
//
// R9 = R6 compute/store/staging EXACTLY (clean traffic: full-width rows,
// wave-local 256B store runs per co-plane, 4-slot window, 512 blocks) with:
//  1. lgkm-only raw barriers (stores + prefetch loads stay in flight),
//  2. 2-deep load pipeline: rgA/rgB ping-pong; write_row's vmcnt wait is
//     for loads issued TWO barriers earlier (fully hidden),
//  3. write_row at iteration top; wasted y0+17 load skipped.

typedef __attribute__((ext_vector_type(8))) short short8;
typedef __attribute__((ext_vector_type(4))) float f32x4;

__device__ __forceinline__ short bf16s(float f) {
    unsigned int u = __builtin_bit_cast(unsigned int, f);
    u += 0x7FFFu + ((u >> 16) & 1u);   // RNE
    return (short)(u >> 16);
}

__device__ __forceinline__ void lgkm_barrier() {
    asm volatile("s_waitcnt lgkmcnt(0)" ::: "memory");
    __builtin_amdgcn_s_barrier();
}

__global__ __launch_bounds__(512, 4)
void bconv2d_kernel(const float* __restrict__ x, const float* __restrict__ wgt,
                    float* __restrict__ out) {
    // unit = slot*1032 + pl*4 + (u ^ ((pl>>1)&3)); slot = gy & 3; pl = gx+1
    // (0..257); u = ci/8. R6-verified: bank-clean, 0-ish conflicts.
    __shared__ short8 lds[4 * 1032];   // 66048 B

    const int tid = threadIdx.x;
    const int y0  = blockIdx.x * 16;   // 16-row strip
    const int n   = blockIdx.y;        // image

    const int l      = tid & 63;
    const int wv     = tid >> 6;       // 0..7
    const int seg    = wv >> 1;        // px segment (64 px)
    const int ch     = wv & 1;         // co half
    const int px0    = seg * 64;
    const int lane15 = l & 15;
    const int lhi    = l >> 4;

    // ---- A fragments: sign(W), this wave's co-half, all 9 taps ----
    short8 afrag[3][3];
    {
        const int co  = ch * 16 + lane15;
        const int ci0 = lhi * 8;
        #pragma unroll
        for (int dy = 0; dy < 3; ++dy)
            #pragma unroll
            for (int dx = 0; dx < 3; ++dx) {
                short8 a;
                #pragma unroll
                for (int j = 0; j < 8; ++j) {
                    float wval = wgt[((co * 32 + ci0 + j) * 3 + dy) * 3 + dx];
                    a[j] = (short)((wval > 0.0f) ? 0x3F80 : 0xBF80);
                }
                afrag[dy][dx] = a;
            }
    }

    const float* xn = x + (size_t)n * 32 * 65536;

    // staging ownership: t = tid + k*512 (k=0,1): u = t>>8, gx = t&255.
    float rgA[2][8], rgB[2][8];

    auto load_row = [&](int gy, float (&rg)[2][8]) {
        if ((unsigned)gy < 256u) {
            #pragma unroll
            for (int k = 0; k < 2; ++k) {
                const int t  = tid + k * 512;
                const int u  = t >> 8;
                const int gx = t & 255;
                const float* src = xn + ((size_t)(u * 8) * 256 + gy) * 256 + gx;
                #pragma unroll
                for (int j = 0; j < 8; ++j) rg[k][j] = src[(size_t)j * 65536];
            }
        } else {
            #pragma unroll
            for (int k = 0; k < 2; ++k)
                #pragma unroll
                for (int j = 0; j < 8; ++j) rg[k][j] = 0.0f;
        }
    };

    auto write_row = [&](int slot, float (&rg)[2][8]) {
        #pragma unroll
        for (int k = 0; k < 2; ++k) {
            const int t  = tid + k * 512;
            const int u  = t >> 8;
            const int pl = 1 + (t & 255);
            short8 v;
            #pragma unroll
            for (int j = 0; j < 8; ++j) v[j] = bf16s(rg[k][j]);
            lds[slot * 1032 + pl * 4 + (u ^ ((pl >> 1) & 3))] = v;
        }
    };

    const float invdiv = 0.05892556509887896f;   // 1/sqrt(288)

    // compute + store one output row (R6-identical; clean 256B store runs)
    auto row_cs = [&](int yy) {
        const int y = y0 + yy;
        f32x4 acc[4];
        #pragma unroll
        for (int tp = 0; tp < 4; ++tp) acc[tp] = (f32x4)0.0f;
        #pragma unroll
        for (int ss = 0; ss < 3; ++ss) {              // input row y-1+ss
            const int sbase = ((yy + ss + 3) & 3) * 1032;
            #pragma unroll
            for (int dx = 0; dx < 3; ++dx)
                #pragma unroll
                for (int tp = 0; tp < 4; ++tp) {
                    const int pl = px0 + tp * 16 + lane15 + dx;
                    short8 b = lds[sbase + pl * 4 + (lhi ^ ((pl >> 1) & 3))];
                    acc[tp] = __builtin_amdgcn_mfma_f32_16x16x32_bf16(
                        afrag[ss][dx], b, acc[tp], 0, 0, 0);
                }
        }
        #pragma unroll
        for (int tp = 0; tp < 4; ++tp)
            #pragma unroll
            for (int q = 0; q < 4; ++q) {
                const int co = ch * 16 + lhi * 4 + q;
                out[(((size_t)n * 32 + co) * 256 + y) * 256 + px0 + tp * 16 + lane15]
                    = acc[tp][q] * invdiv;
            }
    };

    // ---- prologue: slots for rows y0-1, y0, y0+1; A=row y0+2, B=row y0+3 ----
    load_row(y0 - 1, rgA); write_row(3, rgA);
    load_row(y0,     rgA); write_row(0, rgA);
    load_row(y0 + 1, rgA); write_row(1, rgA);
    load_row(y0 + 2, rgA);             // iter 0 writes A
    load_row(y0 + 3, rgB);             // iter 1 writes B
    if (tid < 32) {   // pl=0 (gx=-1) and pl=257 (gx=256): constant zero
        const int slot = tid & 3;
        const int u    = (tid >> 2) & 3;
        const int pl   = (tid >> 4) ? 257 : 0;
        lds[slot * 1032 + pl * 4 + u] = (short8)0;   // swizzle term 0 here
    }
    lgkm_barrier();

    // iter i (row y=y0+i): write row y+2 (loaded at iter i-2), load row y+4
    // (i<=12), compute+store row y, lgkm barrier. Slots mod 4: reads
    // {y-1,y,y+1}, write {y+2} -- disjoint; WAR on slot (y+2)&3 covered by
    // iter i-1's end barrier.
    #pragma unroll 1
    for (int ii = 0; ii < 8; ++ii) {
        const int ye = 2 * ii;          // even iter
        write_row((ye + 2) & 3, rgA);
        if (ii <= 6) load_row(y0 + ye + 4, rgA);
        row_cs(ye);
        lgkm_barrier();

        const int yo = ye + 1;          // odd iter
        if (ii <= 6) write_row((yo + 2) & 3, rgB);   // iter 15: nothing to write
        if (ii <= 5) load_row(y0 + yo + 4, rgB);
        row_cs(yo);
        lgkm_barrier();
    }
}

extern "C" void kernel_launch(void* const* d_in, const int* in_sizes, int n_in,
                              void* d_out, int out_size, void* d_ws, size_t ws_size,
                              hipStream_t stream) {
    const float* x   = (const float*)d_in[0];
    const float* wgt = (const float*)d_in[1];
    float* out = (float*)d_out;
    (void)d_ws; (void)ws_size;
    dim3 grid(16, 32);     // 16-row strips, images
    dim3 block(512);
    bconv2d_kernel<<<grid, block, 0, stream>>>(x, wgt, out);
}